// Round 4
// baseline (611.277 us; speedup 1.0000x reference)
//
#include <hip/hip_runtime.h>

// RowAreaAttention split pipeline:
//  K0 prep: f32->f16 (w_qkv, w_proj, x)
//  K1 gemm8 (8-phase 256x256): QKV = xh @ wq16^T (65536 x 2304 x 768) -> qkv f16
//  K2 attn64: per (group,head) 64x64 attention, O written in-place into Q slot
//  K3 gemm8: out = Qslot @ wp16^T + bias (65536 x 768 x 768) -> f32

#define SCALE 0.125f

typedef _Float16 h16;
typedef h16   half8 __attribute__((ext_vector_type(8)));
typedef float f32x4 __attribute__((ext_vector_type(4)));

typedef const __attribute__((address_space(1))) unsigned int ga_u32;
typedef __attribute__((address_space(3))) unsigned int ls_u32;

// ---------------------------------------------------------------- K0: prep
__device__ __forceinline__ void cvt8(const float* __restrict__ s,
                                     h16* __restrict__ d, int i) {
  const float4 a = ((const float4*)s)[2 * i];
  const float4 b = ((const float4*)s)[2 * i + 1];
  half8 r;
  r[0] = (h16)a.x; r[1] = (h16)a.y; r[2] = (h16)a.z; r[3] = (h16)a.w;
  r[4] = (h16)b.x; r[5] = (h16)b.y; r[6] = (h16)b.z; r[7] = (h16)b.w;
  ((half8*)d)[i] = r;
}

__global__ void prep_cvt(const float* __restrict__ wq, const float* __restrict__ wp,
                         const float* __restrict__ x,
                         h16* __restrict__ wq16, h16* __restrict__ wp16,
                         h16* __restrict__ xh) {
  const int stride = gridDim.x * blockDim.x;
  const int t0 = blockIdx.x * blockDim.x + threadIdx.x;
  for (int i = t0; i < 221184; i += stride) cvt8(wq, wq16, i);   // 2304*768
  for (int i = t0; i < 73728;  i += stride) cvt8(wp, wp16, i);   // 768*768
  for (int i = t0; i < 6291456; i += stride) cvt8(x, xh, i);     // 65536*768
}

__global__ void prep_w_only(const float* __restrict__ wq, const float* __restrict__ wp,
                            h16* __restrict__ wq16, h16* __restrict__ wp16) {
  const int stride = gridDim.x * blockDim.x;
  const int t0 = blockIdx.x * blockDim.x + threadIdx.x;
  for (int i = t0; i < 221184; i += stride) cvt8(wq, wq16, i);
  for (int i = t0; i < 73728;  i += stride) cvt8(wp, wp16, i);
}

// ------------------------------------------------- K1/K3: gemm8 (8-phase 256^2)
// C(M x N) = A(M x 768, row-major, lda) @ B(N x 768, row-major, ldb)^T [+bias]
// 256x256 tile, BK=64, 12 K-tiles, 8 waves (2M x 4N), 512 thr, LDS 128 KB.
// Half-tiles: A half h = tile rows [h*128,h*128+128), B half h = tile cols same.
// Swizzle (involution): element (r,c) of a [128][64] half lives at h16 offset
// r*64 + ((c>>3) ^ ((r>>1)&3))*8 + (c&7); staged via pre-swizzled global src.
// Pipeline per K-tile (4 phases): q0 reads b-frags+a-quad0 & stages A0(kt+1);
// q1 a-quad1 & A1(kt+1),B0(kt+2); q2 a-quad2 & B1(kt+2); q3 a-quad3, then
// counted vmcnt gate (4; 0 at kt=10) before the phase barrier. Never drain mid-loop.
template <bool BIAS, typename OutT>
__launch_bounds__(512, 1)
__global__ void gemm8(const h16* __restrict__ A, int lda,
                      const h16* __restrict__ B, int ldb,
                      const float* __restrict__ bias,
                      OutT* __restrict__ C, int ldc,
                      int ntiles) {
  __shared__ h16 As[2][2][8192];
  __shared__ h16 Bs[2][2][8192];

  const int nwg = gridDim.x;
  const int bid = blockIdx.x;
  const int wg  = (bid & 7) * (nwg >> 3) + (bid >> 3);   // XCD-chunked swizzle
  const int mt = wg / ntiles, nt = wg - mt * ntiles;
  const int m0 = mt * 256, n0 = nt * 256;

  const int tid  = threadIdx.x;
  const int lane = tid & 63;
  const int wv   = tid >> 6;       // 0..7
  const int l16  = lane & 15;
  const int kg   = lane >> 4;      // 0..3
  const int wr   = wv >> 2;        // 0..1  (M half)
  const int wc   = wv & 3;         // 0..3  (N quarter)

  // ---- staging addresses: thread covers chunks wv*128 + i*64 + lane of a half
  const h16* pa[2];
  const h16* pb[2];
  int lo[2];
  #pragma unroll
  for (int i = 0; i < 2; ++i) {
    const int r  = wv * 16 + i * 8 + (lane >> 3);        // row within 128-row half
    const int cg = (lane & 7) ^ ((r >> 1) & 3);          // pre-swizzled src col-group
    pa[i] = A + (size_t)(m0 + r) * lda + cg * 8;
    pb[i] = B + (size_t)(n0 + r) * ldb + cg * 8;
    lo[i] = wv * 1024 + i * 512;                         // h16 offset in half-tile
  }

#define GLDS(srcp, ldsp)                                                       \
  __builtin_amdgcn_global_load_lds((ga_u32*)(const void*)(srcp),               \
                                   (ls_u32*)(void*)(ldsp), 16, 0, 0)
#define STG_A(slot, h, kt)                                                     \
  do {                                                                         \
    GLDS(pa[0] + (size_t)(h) * 128 * lda + (kt) * 64, &As[slot][h][lo[0]]);    \
    GLDS(pa[1] + (size_t)(h) * 128 * lda + (kt) * 64, &As[slot][h][lo[1]]);    \
  } while (0)
#define STG_B(slot, h, kt)                                                     \
  do {                                                                         \
    GLDS(pb[0] + (size_t)(h) * 128 * ldb + (kt) * 64, &Bs[slot][h][lo[0]]);    \
    GLDS(pb[1] + (size_t)(h) * 128 * ldb + (kt) * 64, &Bs[slot][h][lo[1]]);    \
  } while (0)

  // ---- fragment read offsets (h16 units, swizzled)
  const int s     = (l16 >> 1) & 3;
  const int abase = l16 * 64 + (kg ^ s) * 8;                       // + mi*1024 + ks*32
  const int bbase = (wc & 1) * 4096 + l16 * 64 + (kg ^ s) * 8;     // + ni*1024 + ks*32

  f32x4 acc[8][4];
  #pragma unroll
  for (int mi = 0; mi < 8; ++mi)
    #pragma unroll
    for (int ni = 0; ni < 4; ++ni)
      acc[mi][ni] = (f32x4){0.f, 0.f, 0.f, 0.f};

  // ---- prologue: B(0), A(0), B(1); gate oldest 8 loads; barrier
  STG_B(0, 0, 0); STG_B(0, 1, 0);
  STG_A(0, 0, 0); STG_A(0, 1, 0);
  STG_B(1, 0, 1); STG_B(1, 1, 1);
  asm volatile("s_waitcnt vmcnt(4)" ::: "memory");
  __builtin_amdgcn_s_barrier();

  int cur = 0;
  for (int kt = 0; kt < 12; ++kt) {
    const int nx = cur ^ 1;
    const h16* Acur = &As[cur][wr][0];
    const h16* Bcur = &Bs[cur][wc >> 1][0];
    half8 bfr[4][2];

    #pragma unroll
    for (int q = 0; q < 4; ++q) {
      // ds-read this phase's register subtile
      if (q == 0) {
        #pragma unroll
        for (int ni = 0; ni < 4; ++ni)
          #pragma unroll
          for (int ks = 0; ks < 2; ++ks)
            bfr[ni][ks] = *(const half8*)&Bcur[bbase + ni * 1024 + ks * 32];
      }
      half8 af[2][2];
      #pragma unroll
      for (int e = 0; e < 2; ++e)
        #pragma unroll
        for (int ks = 0; ks < 2; ++ks)
          af[e][ks] = *(const half8*)&Acur[abase + (2 * q + e) * 1024 + ks * 32];

      // stage schedule (writes only barrier-proven-dead regions)
      if (q == 0 && kt + 1 < 12) STG_A(nx, 0, kt + 1);
      if (q == 1 && kt + 1 < 12) STG_A(nx, 1, kt + 1);
      if (q == 1 && kt + 2 < 12) STG_B(cur, 0, kt + 2);
      if (q == 2 && kt + 2 < 12) STG_B(cur, 1, kt + 2);

      __builtin_amdgcn_s_barrier();
      asm volatile("s_waitcnt lgkmcnt(0)" ::: "memory");
      __builtin_amdgcn_sched_barrier(0);

      __builtin_amdgcn_s_setprio(1);
      #pragma unroll
      for (int e = 0; e < 2; ++e)
        #pragma unroll
        for (int ni = 0; ni < 4; ++ni)
          #pragma unroll
          for (int ks = 0; ks < 2; ++ks)
            acc[2 * q + e][ni] = __builtin_amdgcn_mfma_f32_16x16x32_f16(
                af[e][ks], bfr[ni][ks], acc[2 * q + e][ni], 0, 0, 0);
      __builtin_amdgcn_s_setprio(0);

      // counted vmcnt gate for next K-tile's data (cross-wave via the barrier)
      if (q == 3) {
        if (kt < 10)       asm volatile("s_waitcnt vmcnt(4)" ::: "memory");
        else if (kt == 10) asm volatile("s_waitcnt vmcnt(0)" ::: "memory");
      }
      __builtin_amdgcn_s_barrier();
    }
    cur = nx;
  }
#undef STG_A
#undef STG_B
#undef GLDS

  // ---- epilogue
  float bv[4];
  if (BIAS) {
    #pragma unroll
    for (int ni = 0; ni < 4; ++ni) bv[ni] = bias[n0 + wc * 64 + ni * 16 + l16];
  }
  #pragma unroll
  for (int mi = 0; mi < 8; ++mi) {
    #pragma unroll
    for (int ni = 0; ni < 4; ++ni) {
      const int col = n0 + wc * 64 + ni * 16 + l16;
      #pragma unroll
      for (int j = 0; j < 4; ++j) {
        const int row = m0 + wr * 128 + mi * 16 + kg * 4 + j;
        if (BIAS) C[(size_t)row * ldc + col] = (OutT)(acc[mi][ni][j] + bv[ni]);
        else      C[(size_t)row * ldc + col] = (OutT)acc[mi][ni][j];
      }
    }
  }
}

// ---------------------------------------------------------------- K2: attn
// One WG (4 waves) per (group, head). qkv row-major [65536][2304] f16.
// Q slice at col h*64, K at +768, V at +1536. O overwrites the Q slice.
__global__ void attn64(h16* __restrict__ qkv) {
  __shared__ h16 vt[64][72];   // V^T [dim][token]
  __shared__ h16 ps[64][72];   // P, then O

  const int bid = blockIdx.x;
  const int g = bid / 12, h = bid - g * 12;
  const int tid = threadIdx.x, lane = tid & 63, wv = tid >> 6;
  const int l16 = lane & 15, kg = lane >> 4;

  h16* qp = qkv + (size_t)g * 64 * 2304 + h * 64;
  const h16* kp = qp + 768;
  const h16* vp = qp + 1536;

  // stage V^T
  #pragma unroll
  for (int c = tid; c < 512; c += 256) {
    const int tok = c >> 3, d0 = (c & 7) * 8;
    const half8 v = *(const half8*)(vp + (size_t)tok * 2304 + d0);
    #pragma unroll
    for (int u = 0; u < 8; ++u) vt[d0 + u][tok] = v[u];
  }

  // S = Q K^T for rows [wv*16, wv*16+16)
  const int qrow = wv * 16 + l16;
  half8 qa[2];
  #pragma unroll
  for (int kb = 0; kb < 2; ++kb)
    qa[kb] = *(const half8*)(qp + (size_t)qrow * 2304 + kb * 32 + kg * 8);

  f32x4 sacc[4];
  #pragma unroll
  for (int cb = 0; cb < 4; ++cb) sacc[cb] = (f32x4){0.f, 0.f, 0.f, 0.f};
  #pragma unroll
  for (int cb = 0; cb < 4; ++cb)
    #pragma unroll
    for (int kb = 0; kb < 2; ++kb) {
      const half8 kf = *(const half8*)(kp + (size_t)(cb * 16 + l16) * 2304 + kb * 32 + kg * 8);
      sacc[cb] = __builtin_amdgcn_mfma_f32_16x16x32_f16(qa[kb], kf, sacc[cb], 0, 0, 0);
    }

  // max-free softmax (|S*scale| << 88): rows wv*16 + kg*4 + j
  float e[4][4], rs[4];
  #pragma unroll
  for (int j = 0; j < 4; ++j) {
    float t = 0.f;
    #pragma unroll
    for (int cb = 0; cb < 4; ++cb) { e[cb][j] = __expf(sacc[cb][j] * SCALE); t += e[cb][j]; }
    rs[j] = t;
  }
  #pragma unroll
  for (int m = 1; m < 16; m <<= 1)
    #pragma unroll
    for (int j = 0; j < 4; ++j) rs[j] += __shfl_xor(rs[j], m);
  #pragma unroll
  for (int j = 0; j < 4; ++j) rs[j] = __fdividef(1.0f, rs[j]);

  const int prow = wv * 16 + kg * 4;
  #pragma unroll
  for (int cb = 0; cb < 4; ++cb)
    #pragma unroll
    for (int j = 0; j < 4; ++j)
      ps[prow + j][cb * 16 + l16] = (h16)(e[cb][j] * rs[j]);

  __syncthreads();   // vt staged by all waves

  // O = P V
  half8 pa[2];
  #pragma unroll
  for (int kb = 0; kb < 2; ++kb)
    pa[kb] = *(const half8*)&ps[wv * 16 + l16][kb * 32 + kg * 8];
  f32x4 oacc[4];
  #pragma unroll
  for (int cb = 0; cb < 4; ++cb) oacc[cb] = (f32x4){0.f, 0.f, 0.f, 0.f};
  #pragma unroll
  for (int cb = 0; cb < 4; ++cb)
    #pragma unroll
    for (int kb = 0; kb < 2; ++kb) {
      const half8 vf = *(const half8*)&vt[cb * 16 + l16][kb * 32 + kg * 8];
      oacc[cb] = __builtin_amdgcn_mfma_f32_16x16x32_f16(pa[kb], vf, oacc[cb], 0, 0, 0);
    }

  // O -> ps, then vectorized in-place store to Q slot
  #pragma unroll
  for (int cb = 0; cb < 4; ++cb)
    #pragma unroll
    for (int j = 0; j < 4; ++j)
      ps[prow + j][cb * 16 + l16] = (h16)oacc[cb][j];
  __syncthreads();
  #pragma unroll
  for (int c = tid; c < 512; c += 256) {
    const int tok = c >> 3, d0 = (c & 7) * 8;
    *(half8*)(qp + (size_t)tok * 2304 + d0) = *(const half8*)&ps[tok][d0];
  }
}

// ------------------------------------------- fallback: fused kernel (small ws)
template <typename WT>
__device__ __forceinline__ half8 loadw8(const WT* p);
template <>
__device__ __forceinline__ half8 loadw8<h16>(const h16* p) { return *(const half8*)p; }
template <>
__device__ __forceinline__ half8 loadw8<float>(const float* p) {
  const float4 a = *(const float4*)p;
  const float4 b = *(const float4*)(p + 4);
  half8 r;
  r[0] = (h16)a.x; r[1] = (h16)a.y; r[2] = (h16)a.z; r[3] = (h16)a.w;
  r[4] = (h16)b.x; r[5] = (h16)b.y; r[6] = (h16)b.z; r[7] = (h16)b.w;
  return r;
}

template <typename WT>
__launch_bounds__(512, 2)
__global__ void fused_fb(const float* __restrict__ x,
                         const WT* __restrict__ wq,
                         const WT* __restrict__ wp,
                         const float* __restrict__ bias,
                         float* __restrict__ out) {
  __shared__ h16   xs[64][776];
  __shared__ h16   qs[64][72];
  __shared__ h16   ks[64][72];
  __shared__ h16   vt[64][72];
  __shared__ float sS[64][68];

  const int g = blockIdx.x, tid = threadIdx.x;
  const int wv = tid >> 6, lane = tid & 63, l16 = lane & 15, kg = lane >> 4;

  const float* xg = x + (size_t)g * (64 * 768);
  #pragma unroll
  for (int i = 0; i < 24; ++i) {
    const int idx = tid + i * 512;
    const int row = idx / 192;
    const int c4  = (idx - row * 192) * 4;
    const float4 v = ((const float4*)xg)[idx];
    h16* p = &xs[row][c4];
    p[0] = (h16)v.x; p[1] = (h16)v.y; p[2] = (h16)v.z; p[3] = (h16)v.w;
  }

  f32x4 acc[4][6];
  #pragma unroll
  for (int a = 0; a < 4; ++a)
    #pragma unroll
    for (int b = 0; b < 6; ++b) acc[a][b] = (f32x4){0.f, 0.f, 0.f, 0.f};

  float bcol[6];
  #pragma unroll
  for (int cb = 0; cb < 6; ++cb) bcol[cb] = bias[wv * 96 + cb * 16 + l16];

  const int r0 = (wv & 1) * 32, c0 = (wv >> 1) * 48;
  const int rS = (wv >> 1) * 16, cS = (wv & 1) * 32;
  __syncthreads();

  for (int h = 0; h < 12; ++h) {
    f32x4 facc[2][3];
    #pragma unroll
    for (int a = 0; a < 2; ++a)
      #pragma unroll
      for (int b = 0; b < 3; ++b) facc[a][b] = (f32x4){0.f, 0.f, 0.f, 0.f};
    int wrow[3];
    #pragma unroll
    for (int cb = 0; cb < 3; ++cb) {
      const int n = c0 + cb * 16;
      wrow[cb] = (n >> 6) * 768 + h * 64 + (n & 63) + l16;
    }
    for (int k0 = 0; k0 < 768; k0 += 32) {
      const half8 a0 = *(const half8*)&xs[r0 + l16][k0 + kg * 8];
      const half8 a1 = *(const half8*)&xs[r0 + 16 + l16][k0 + kg * 8];
      #pragma unroll
      for (int cb = 0; cb < 3; ++cb) {
        const half8 b = loadw8<WT>(wq + (size_t)wrow[cb] * 768 + k0 + kg * 8);
        facc[0][cb] = __builtin_amdgcn_mfma_f32_16x16x32_f16(a0, b, facc[0][cb], 0, 0, 0);
        facc[1][cb] = __builtin_amdgcn_mfma_f32_16x16x32_f16(a1, b, facc[1][cb], 0, 0, 0);
      }
    }
    #pragma unroll
    for (int rb = 0; rb < 2; ++rb)
      #pragma unroll
      for (int cb = 0; cb < 3; ++cb) {
        const int col = c0 + cb * 16 + l16;
        const int rowb = r0 + rb * 16 + kg * 4;
        if (col < 64) {
          #pragma unroll
          for (int j = 0; j < 4; ++j) qs[rowb + j][col] = (h16)facc[rb][cb][j];
        } else if (col < 128) {
          #pragma unroll
          for (int j = 0; j < 4; ++j) ks[rowb + j][col - 64] = (h16)facc[rb][cb][j];
        } else {
          #pragma unroll
          for (int j = 0; j < 4; ++j) vt[col - 128][rowb + j] = (h16)facc[rb][cb][j];
        }
      }
    __syncthreads();

    f32x4 sacc[2];
    sacc[0] = (f32x4){0.f, 0.f, 0.f, 0.f};
    sacc[1] = (f32x4){0.f, 0.f, 0.f, 0.f};
    #pragma unroll
    for (int k0 = 0; k0 < 64; k0 += 32) {
      const half8 aq = *(const half8*)&qs[rS + l16][k0 + kg * 8];
      const half8 b0 = *(const half8*)&ks[cS + l16][k0 + kg * 8];
      const half8 b1 = *(const half8*)&ks[cS + 16 + l16][k0 + kg * 8];
      sacc[0] = __builtin_amdgcn_mfma_f32_16x16x32_f16(aq, b0, sacc[0], 0, 0, 0);
      sacc[1] = __builtin_amdgcn_mfma_f32_16x16x32_f16(aq, b1, sacc[1], 0, 0, 0);
    }
    #pragma unroll
    for (int t = 0; t < 2; ++t)
      #pragma unroll
      for (int j = 0; j < 4; ++j)
        sS[rS + kg * 4 + j][cS + t * 16 + l16] = sacc[t][j] * SCALE;
    __syncthreads();

    {
      const int row = tid >> 3, j0 = (tid & 7) * 8;
      float v0[8];
      #pragma unroll
      for (int i = 0; i < 8; ++i) v0[i] = sS[row][j0 + i];
      float m = v0[0];
      #pragma unroll
      for (int i = 1; i < 8; ++i) m = fmaxf(m, v0[i]);
      m = fmaxf(m, __shfl_xor(m, 1));
      m = fmaxf(m, __shfl_xor(m, 2));
      m = fmaxf(m, __shfl_xor(m, 4));
      float e[8], ssum = 0.f;
      #pragma unroll
      for (int i = 0; i < 8; ++i) { e[i] = __expf(v0[i] - m); ssum += e[i]; }
      ssum += __shfl_xor(ssum, 1);
      ssum += __shfl_xor(ssum, 2);
      ssum += __shfl_xor(ssum, 4);
      const float inv = 1.0f / ssum;
      #pragma unroll
      for (int i = 0; i < 8; ++i) qs[row][j0 + i] = (h16)(e[i] * inv);
    }
    __syncthreads();

    f32x4 oacc[2];
    oacc[0] = (f32x4){0.f, 0.f, 0.f, 0.f};
    oacc[1] = (f32x4){0.f, 0.f, 0.f, 0.f};
    #pragma unroll
    for (int k0 = 0; k0 < 64; k0 += 32) {
      const half8 ap = *(const half8*)&qs[rS + l16][k0 + kg * 8];
      const half8 b0 = *(const half8*)&vt[cS + l16][k0 + kg * 8];
      const half8 b1 = *(const half8*)&vt[cS + 16 + l16][k0 + kg * 8];
      oacc[0] = __builtin_amdgcn_mfma_f32_16x16x32_f16(ap, b0, oacc[0], 0, 0, 0);
      oacc[1] = __builtin_amdgcn_mfma_f32_16x16x32_f16(ap, b1, oacc[1], 0, 0, 0);
    }
    #pragma unroll
    for (int t = 0; t < 2; ++t)
      #pragma unroll
      for (int j = 0; j < 4; ++j)
        ks[rS + kg * 4 + j][cS + t * 16 + l16] = (h16)oacc[t][j];
    __syncthreads();

    #pragma unroll
    for (int k0 = 0; k0 < 64; k0 += 32) {
      half8 ah[4];
      #pragma unroll
      for (int rb = 0; rb < 4; ++rb)
        ah[rb] = *(const half8*)&ks[rb * 16 + l16][k0 + kg * 8];
      #pragma unroll
      for (int cb = 0; cb < 6; ++cb) {
        const int ocol = wv * 96 + cb * 16 + l16;
        const half8 bw = loadw8<WT>(wp + (size_t)ocol * 768 + h * 64 + k0 + kg * 8);
        #pragma unroll
        for (int rb = 0; rb < 4; ++rb)
          acc[rb][cb] = __builtin_amdgcn_mfma_f32_16x16x32_f16(ah[rb], bw, acc[rb][cb], 0, 0, 0);
      }
    }
    __syncthreads();
  }

  float* og = out + (size_t)g * (64 * 768);
  #pragma unroll
  for (int rb = 0; rb < 4; ++rb)
    #pragma unroll
    for (int cb = 0; cb < 6; ++cb) {
      const int col = wv * 96 + cb * 16 + l16;
      #pragma unroll
      for (int j = 0; j < 4; ++j) {
        const int row = rb * 16 + kg * 4 + j;
        og[(size_t)row * 768 + col] = acc[rb][cb][j] + bcol[cb];
      }
    }
}

// ---------------------------------------------------------------- launch
extern "C" void kernel_launch(void* const* d_in, const int* in_sizes, int n_in,
                              void* d_out, int out_size, void* d_ws, size_t ws_size,
                              hipStream_t stream) {
  const float* x     = (const float*)d_in[0];
  const float* wqkv  = (const float*)d_in[1];
  const float* wproj = (const float*)d_in[2];
  const float* bias  = (const float*)d_in[3];
  float* out = (float*)d_out;

  const size_t SZ_WQ  = (size_t)2304 * 768 * sizeof(h16);
  const size_t SZ_WP  = (size_t)768 * 768 * sizeof(h16);
  const size_t SZ_XH  = (size_t)65536 * 768 * sizeof(h16);
  const size_t SZ_QKV = (size_t)65536 * 2304 * sizeof(h16);

  if (ws_size >= SZ_WQ + SZ_WP + SZ_XH + SZ_QKV) {
    h16* wq16 = (h16*)d_ws;
    h16* wp16 = (h16*)((char*)d_ws + SZ_WQ);
    h16* xh   = (h16*)((char*)d_ws + SZ_WQ + SZ_WP);
    h16* qkv  = (h16*)((char*)d_ws + SZ_WQ + SZ_WP + SZ_XH);

    prep_cvt<<<2048, 256, 0, stream>>>(wqkv, wproj, x, wq16, wp16, xh);
    gemm8<false, h16><<<2304, 512, 0, stream>>>(xh, 768, wq16, 768, nullptr, qkv, 2304, 9);
    attn64<<<12288, 256, 0, stream>>>(qkv);
    gemm8<true, float><<<768, 512, 0, stream>>>(qkv, 2304, wp16, 768, bias, out, 768, 3);
  } else if (ws_size >= SZ_WQ + SZ_WP) {
    h16* wq16 = (h16*)d_ws;
    h16* wp16 = (h16*)((char*)d_ws + SZ_WQ);
    prep_w_only<<<1024, 256, 0, stream>>>(wqkv, wproj, wq16, wp16);
    fused_fb<h16><<<1024, 512, 0, stream>>>(x, wq16, wp16, bias, out);
  } else {
    fused_fb<float><<<1024, 512, 0, stream>>>(x, wqkv, wproj, bias, out);
  }
}

// Round 5
// 592.942 us; speedup vs baseline: 1.0309x; 1.0309x over previous
//
#include <hip/hip_runtime.h>

// RowAreaAttention split pipeline:
//  K0 prep: f32->f16 (w_qkv, w_proj, x)
//  K1 gemm8 (8-phase 256x256): QKV = xh @ wq16^T (65536 x 2304 x 768) -> qkv f16
//  K2 attn64: per (group,head) 64x64 attention, O written in-place into Q slot
//  K3 gemm8: out = Qslot @ wp16^T + bias (65536 x 768 x 768) -> f32

#define SCALE 0.125f

typedef _Float16 h16;
typedef h16   half8 __attribute__((ext_vector_type(8)));
typedef float f32x4 __attribute__((ext_vector_type(4)));

typedef const __attribute__((address_space(1))) unsigned int ga_u32;
typedef __attribute__((address_space(3))) unsigned int ls_u32;

// ---------------------------------------------------------------- K0: prep
__device__ __forceinline__ void cvt8(const float* __restrict__ s,
                                     h16* __restrict__ d, int i) {
  const float4 a = ((const float4*)s)[2 * i];
  const float4 b = ((const float4*)s)[2 * i + 1];
  half8 r;
  r[0] = (h16)a.x; r[1] = (h16)a.y; r[2] = (h16)a.z; r[3] = (h16)a.w;
  r[4] = (h16)b.x; r[5] = (h16)b.y; r[6] = (h16)b.z; r[7] = (h16)b.w;
  ((half8*)d)[i] = r;
}

__global__ void prep_cvt(const float* __restrict__ wq, const float* __restrict__ wp,
                         const float* __restrict__ x,
                         h16* __restrict__ wq16, h16* __restrict__ wp16,
                         h16* __restrict__ xh) {
  const int stride = gridDim.x * blockDim.x;
  const int t0 = blockIdx.x * blockDim.x + threadIdx.x;
  for (int i = t0; i < 221184; i += stride) cvt8(wq, wq16, i);   // 2304*768
  for (int i = t0; i < 73728;  i += stride) cvt8(wp, wp16, i);   // 768*768
  for (int i = t0; i < 6291456; i += stride) cvt8(x, xh, i);     // 65536*768
}

__global__ void prep_w_only(const float* __restrict__ wq, const float* __restrict__ wp,
                            h16* __restrict__ wq16, h16* __restrict__ wp16) {
  const int stride = gridDim.x * blockDim.x;
  const int t0 = blockIdx.x * blockDim.x + threadIdx.x;
  for (int i = t0; i < 221184; i += stride) cvt8(wq, wq16, i);
  for (int i = t0; i < 73728;  i += stride) cvt8(wp, wp16, i);
}

// ------------------------------------------------- K1/K3: gemm8 (8-phase 256^2)
// C(M x N) = A(M x 768, row-major, lda) @ B(N x 768, row-major, ldb)^T [+bias]
// 256x256 tile, BK=64, 12 K-tiles, 8 waves (2M x 4N), 512 thr, LDS 128 KB.
// Swizzle (involution, FULL 3-bit col-group -- 2-way-free on ds_read_b128):
// element (r,c) of a [128][64]-h16 half lives at r*64 + ((c>>3) ^ (r&7))*8 + (c&7).
// Staged via pre-swizzled global src (rule #21 both-sides): lane's src col-group
// = (lane&7) ^ (r&7); permutes within each 128B row segment, coalescing intact.
// Pipeline per K-tile (4 phases): q0 reads b-frags+a-quad0 & stages A0(kt+1);
// q1 a-quad1 & A1(kt+1),B0(kt+2); q2 a-quad2 & B1(kt+2); q3 a-quad3, then
// counted vmcnt gate (4; 0 at kt=10) before the phase barrier. Never drain mid-loop.
template <bool BIAS, typename OutT>
__launch_bounds__(512, 1)
__global__ void gemm8(const h16* __restrict__ A, int lda,
                      const h16* __restrict__ B, int ldb,
                      const float* __restrict__ bias,
                      OutT* __restrict__ C, int ldc,
                      int ntiles) {
  __shared__ h16 As[2][2][8192];
  __shared__ h16 Bs[2][2][8192];

  const int nwg = gridDim.x;
  const int bid = blockIdx.x;
  const int wg  = (bid & 7) * (nwg >> 3) + (bid >> 3);   // XCD-chunked swizzle
  const int mt = wg / ntiles, nt = wg - mt * ntiles;
  const int m0 = mt * 256, n0 = nt * 256;

  const int tid  = threadIdx.x;
  const int lane = tid & 63;
  const int wv   = tid >> 6;       // 0..7
  const int l16  = lane & 15;
  const int kg   = lane >> 4;      // 0..3
  const int wr   = wv >> 2;        // 0..1  (M half)
  const int wc   = wv & 3;         // 0..3  (N quarter)

  // ---- staging addresses: thread covers chunk (row r, slot lane&7) of a half
  const h16* pa[2];
  const h16* pb[2];
  int lo[2];
  #pragma unroll
  for (int i = 0; i < 2; ++i) {
    const int r  = wv * 16 + i * 8 + (lane >> 3);        // row within 128-row half
    const int cg = (lane & 7) ^ (r & 7);                 // pre-swizzled src col-group
    pa[i] = A + (size_t)(m0 + r) * lda + cg * 8;
    pb[i] = B + (size_t)(n0 + r) * ldb + cg * 8;
    lo[i] = wv * 1024 + i * 512;                         // h16 offset in half-tile
  }

#define GLDS(srcp, ldsp)                                                       \
  __builtin_amdgcn_global_load_lds((ga_u32*)(const void*)(srcp),               \
                                   (ls_u32*)(void*)(ldsp), 16, 0, 0)
#define STG_A(slot, h, kt)                                                     \
  do {                                                                         \
    GLDS(pa[0] + (size_t)(h) * 128 * lda + (kt) * 64, &As[slot][h][lo[0]]);    \
    GLDS(pa[1] + (size_t)(h) * 128 * lda + (kt) * 64, &As[slot][h][lo[1]]);    \
  } while (0)
#define STG_B(slot, h, kt)                                                     \
  do {                                                                         \
    GLDS(pb[0] + (size_t)(h) * 128 * ldb + (kt) * 64, &Bs[slot][h][lo[0]]);    \
    GLDS(pb[1] + (size_t)(h) * 128 * ldb + (kt) * 64, &Bs[slot][h][lo[1]]);    \
  } while (0)

  // ---- fragment read offsets (h16 units, swizzled; row&7 == l16&7)
  const int r7 = l16 & 7;
  int aoff[2], boff[2];
  #pragma unroll
  for (int ks = 0; ks < 2; ++ks) {
    aoff[ks] = l16 * 64 + ((ks * 4 + kg) ^ r7) * 8;
    boff[ks] = (wc & 1) * 4096 + l16 * 64 + ((ks * 4 + kg) ^ r7) * 8;
  }

  f32x4 acc[8][4];
  #pragma unroll
  for (int mi = 0; mi < 8; ++mi)
    #pragma unroll
    for (int ni = 0; ni < 4; ++ni)
      acc[mi][ni] = (f32x4){0.f, 0.f, 0.f, 0.f};

  // ---- prologue: B(0), A(0), B(1); gate oldest 8 loads; barrier
  STG_B(0, 0, 0); STG_B(0, 1, 0);
  STG_A(0, 0, 0); STG_A(0, 1, 0);
  STG_B(1, 0, 1); STG_B(1, 1, 1);
  asm volatile("s_waitcnt vmcnt(4)" ::: "memory");
  __builtin_amdgcn_s_barrier();

  int cur = 0;
  for (int kt = 0; kt < 12; ++kt) {
    const int nx = cur ^ 1;
    const h16* Acur = &As[cur][wr][0];
    const h16* Bcur = &Bs[cur][wc >> 1][0];
    half8 bfr[4][2];

    #pragma unroll
    for (int q = 0; q < 4; ++q) {
      // ds-read this phase's register subtile
      if (q == 0) {
        #pragma unroll
        for (int ni = 0; ni < 4; ++ni)
          #pragma unroll
          for (int ks = 0; ks < 2; ++ks)
            bfr[ni][ks] = *(const half8*)&Bcur[boff[ks] + ni * 1024];
      }
      half8 af[2][2];
      #pragma unroll
      for (int e = 0; e < 2; ++e)
        #pragma unroll
        for (int ks = 0; ks < 2; ++ks)
          af[e][ks] = *(const half8*)&Acur[aoff[ks] + (2 * q + e) * 1024];

      // stage schedule (writes only barrier-proven-dead regions)
      if (q == 0 && kt + 1 < 12) STG_A(nx, 0, kt + 1);
      if (q == 1 && kt + 1 < 12) STG_A(nx, 1, kt + 1);
      if (q == 1 && kt + 2 < 12) STG_B(cur, 0, kt + 2);
      if (q == 2 && kt + 2 < 12) STG_B(cur, 1, kt + 2);

      __builtin_amdgcn_s_barrier();
      asm volatile("s_waitcnt lgkmcnt(0)" ::: "memory");
      __builtin_amdgcn_sched_barrier(0);

      __builtin_amdgcn_s_setprio(1);
      #pragma unroll
      for (int e = 0; e < 2; ++e)
        #pragma unroll
        for (int ni = 0; ni < 4; ++ni)
          #pragma unroll
          for (int ks = 0; ks < 2; ++ks)
            acc[2 * q + e][ni] = __builtin_amdgcn_mfma_f32_16x16x32_f16(
                af[e][ks], bfr[ni][ks], acc[2 * q + e][ni], 0, 0, 0);
      __builtin_amdgcn_s_setprio(0);

      // counted vmcnt gate for next K-tile's data (cross-wave via the barrier)
      if (q == 3) {
        if (kt < 10)       asm volatile("s_waitcnt vmcnt(4)" ::: "memory");
        else if (kt == 10) asm volatile("s_waitcnt vmcnt(0)" ::: "memory");
      }
      __builtin_amdgcn_s_barrier();
    }
    cur = nx;
  }
#undef STG_A
#undef STG_B
#undef GLDS

  // ---- epilogue
  float bv[4];
  if (BIAS) {
    #pragma unroll
    for (int ni = 0; ni < 4; ++ni) bv[ni] = bias[n0 + wc * 64 + ni * 16 + l16];
  }
  #pragma unroll
  for (int mi = 0; mi < 8; ++mi) {
    #pragma unroll
    for (int ni = 0; ni < 4; ++ni) {
      const int col = n0 + wc * 64 + ni * 16 + l16;
      #pragma unroll
      for (int j = 0; j < 4; ++j) {
        const int row = m0 + wr * 128 + mi * 16 + kg * 4 + j;
        if (BIAS) C[(size_t)row * ldc + col] = (OutT)(acc[mi][ni][j] + bv[ni]);
        else      C[(size_t)row * ldc + col] = (OutT)acc[mi][ni][j];
      }
    }
  }
}

// ---------------------------------------------------------------- K2: attn
// One WG (4 waves) per (group, head). qkv row-major [65536][2304] f16.
// Q slice at col h*64, K at +768, V at +1536. O overwrites the Q slice.
__global__ void attn64(h16* __restrict__ qkv) {
  __shared__ h16 vt[64][72];   // V^T [dim][token]
  __shared__ h16 ps[64][72];   // P, then O

  const int bid = blockIdx.x;
  const int g = bid / 12, h = bid - g * 12;
  const int tid = threadIdx.x, lane = tid & 63, wv = tid >> 6;
  const int l16 = lane & 15, kg = lane >> 4;

  h16* qp = qkv + (size_t)g * 64 * 2304 + h * 64;
  const h16* kp = qp + 768;
  const h16* vp = qp + 1536;

  // stage V^T
  #pragma unroll
  for (int c = tid; c < 512; c += 256) {
    const int tok = c >> 3, d0 = (c & 7) * 8;
    const half8 v = *(const half8*)(vp + (size_t)tok * 2304 + d0);
    #pragma unroll
    for (int u = 0; u < 8; ++u) vt[d0 + u][tok] = v[u];
  }

  // S = Q K^T for rows [wv*16, wv*16+16)
  const int qrow = wv * 16 + l16;
  half8 qa[2];
  #pragma unroll
  for (int kb = 0; kb < 2; ++kb)
    qa[kb] = *(const half8*)(qp + (size_t)qrow * 2304 + kb * 32 + kg * 8);

  f32x4 sacc[4];
  #pragma unroll
  for (int cb = 0; cb < 4; ++cb) sacc[cb] = (f32x4){0.f, 0.f, 0.f, 0.f};
  #pragma unroll
  for (int cb = 0; cb < 4; ++cb)
    #pragma unroll
    for (int kb = 0; kb < 2; ++kb) {
      const half8 kf = *(const half8*)(kp + (size_t)(cb * 16 + l16) * 2304 + kb * 32 + kg * 8);
      sacc[cb] = __builtin_amdgcn_mfma_f32_16x16x32_f16(qa[kb], kf, sacc[cb], 0, 0, 0);
    }

  // max-free softmax (|S*scale| << 88): rows wv*16 + kg*4 + j
  float e[4][4], rs[4];
  #pragma unroll
  for (int j = 0; j < 4; ++j) {
    float t = 0.f;
    #pragma unroll
    for (int cb = 0; cb < 4; ++cb) { e[cb][j] = __expf(sacc[cb][j] * SCALE); t += e[cb][j]; }
    rs[j] = t;
  }
  #pragma unroll
  for (int m = 1; m < 16; m <<= 1)
    #pragma unroll
    for (int j = 0; j < 4; ++j) rs[j] += __shfl_xor(rs[j], m);
  #pragma unroll
  for (int j = 0; j < 4; ++j) rs[j] = __fdividef(1.0f, rs[j]);

  const int prow = wv * 16 + kg * 4;
  #pragma unroll
  for (int cb = 0; cb < 4; ++cb)
    #pragma unroll
    for (int j = 0; j < 4; ++j)
      ps[prow + j][cb * 16 + l16] = (h16)(e[cb][j] * rs[j]);

  __syncthreads();   // vt staged by all waves

  // O = P V
  half8 pa[2];
  #pragma unroll
  for (int kb = 0; kb < 2; ++kb)
    pa[kb] = *(const half8*)&ps[wv * 16 + l16][kb * 32 + kg * 8];
  f32x4 oacc[4];
  #pragma unroll
  for (int cb = 0; cb < 4; ++cb) oacc[cb] = (f32x4){0.f, 0.f, 0.f, 0.f};
  #pragma unroll
  for (int cb = 0; cb < 4; ++cb)
    #pragma unroll
    for (int kb = 0; kb < 2; ++kb) {
      const half8 vf = *(const half8*)&vt[cb * 16 + l16][kb * 32 + kg * 8];
      oacc[cb] = __builtin_amdgcn_mfma_f32_16x16x32_f16(pa[kb], vf, oacc[cb], 0, 0, 0);
    }

  // O -> ps, then vectorized in-place store to Q slot
  #pragma unroll
  for (int cb = 0; cb < 4; ++cb)
    #pragma unroll
    for (int j = 0; j < 4; ++j)
      ps[prow + j][cb * 16 + l16] = (h16)oacc[cb][j];
  __syncthreads();
  #pragma unroll
  for (int c = tid; c < 512; c += 256) {
    const int tok = c >> 3, d0 = (c & 7) * 8;
    *(half8*)(qp + (size_t)tok * 2304 + d0) = *(const half8*)&ps[tok][d0];
  }
}

// ------------------------------------------- fallback: fused kernel (small ws)
template <typename WT>
__device__ __forceinline__ half8 loadw8(const WT* p);
template <>
__device__ __forceinline__ half8 loadw8<h16>(const h16* p) { return *(const half8*)p; }
template <>
__device__ __forceinline__ half8 loadw8<float>(const float* p) {
  const float4 a = *(const float4*)p;
  const float4 b = *(const float4*)(p + 4);
  half8 r;
  r[0] = (h16)a.x; r[1] = (h16)a.y; r[2] = (h16)a.z; r[3] = (h16)a.w;
  r[4] = (h16)b.x; r[5] = (h16)b.y; r[6] = (h16)b.z; r[7] = (h16)b.w;
  return r;
}

template <typename WT>
__launch_bounds__(512, 2)
__global__ void fused_fb(const float* __restrict__ x,
                         const WT* __restrict__ wq,
                         const WT* __restrict__ wp,
                         const float* __restrict__ bias,
                         float* __restrict__ out) {
  __shared__ h16   xs[64][776];
  __shared__ h16   qs[64][72];
  __shared__ h16   ks[64][72];
  __shared__ h16   vt[64][72];
  __shared__ float sS[64][68];

  const int g = blockIdx.x, tid = threadIdx.x;
  const int wv = tid >> 6, lane = tid & 63, l16 = lane & 15, kg = lane >> 4;

  const float* xg = x + (size_t)g * (64 * 768);
  #pragma unroll
  for (int i = 0; i < 24; ++i) {
    const int idx = tid + i * 512;
    const int row = idx / 192;
    const int c4  = (idx - row * 192) * 4;
    const float4 v = ((const float4*)xg)[idx];
    h16* p = &xs[row][c4];
    p[0] = (h16)v.x; p[1] = (h16)v.y; p[2] = (h16)v.z; p[3] = (h16)v.w;
  }

  f32x4 acc[4][6];
  #pragma unroll
  for (int a = 0; a < 4; ++a)
    #pragma unroll
    for (int b = 0; b < 6; ++b) acc[a][b] = (f32x4){0.f, 0.f, 0.f, 0.f};

  float bcol[6];
  #pragma unroll
  for (int cb = 0; cb < 6; ++cb) bcol[cb] = bias[wv * 96 + cb * 16 + l16];

  const int r0 = (wv & 1) * 32, c0 = (wv >> 1) * 48;
  const int rS = (wv >> 1) * 16, cS = (wv & 1) * 32;
  __syncthreads();

  for (int h = 0; h < 12; ++h) {
    f32x4 facc[2][3];
    #pragma unroll
    for (int a = 0; a < 2; ++a)
      #pragma unroll
      for (int b = 0; b < 3; ++b) facc[a][b] = (f32x4){0.f, 0.f, 0.f, 0.f};
    int wrow[3];
    #pragma unroll
    for (int cb = 0; cb < 3; ++cb) {
      const int n = c0 + cb * 16;
      wrow[cb] = (n >> 6) * 768 + h * 64 + (n & 63) + l16;
    }
    for (int k0 = 0; k0 < 768; k0 += 32) {
      const half8 a0 = *(const half8*)&xs[r0 + l16][k0 + kg * 8];
      const half8 a1 = *(const half8*)&xs[r0 + 16 + l16][k0 + kg * 8];
      #pragma unroll
      for (int cb = 0; cb < 3; ++cb) {
        const half8 b = loadw8<WT>(wq + (size_t)wrow[cb] * 768 + k0 + kg * 8);
        facc[0][cb] = __builtin_amdgcn_mfma_f32_16x16x32_f16(a0, b, facc[0][cb], 0, 0, 0);
        facc[1][cb] = __builtin_amdgcn_mfma_f32_16x16x32_f16(a1, b, facc[1][cb], 0, 0, 0);
      }
    }
    #pragma unroll
    for (int rb = 0; rb < 2; ++rb)
      #pragma unroll
      for (int cb = 0; cb < 3; ++cb) {
        const int col = c0 + cb * 16 + l16;
        const int rowb = r0 + rb * 16 + kg * 4;
        if (col < 64) {
          #pragma unroll
          for (int j = 0; j < 4; ++j) qs[rowb + j][col] = (h16)facc[rb][cb][j];
        } else if (col < 128) {
          #pragma unroll
          for (int j = 0; j < 4; ++j) ks[rowb + j][col - 64] = (h16)facc[rb][cb][j];
        } else {
          #pragma unroll
          for (int j = 0; j < 4; ++j) vt[col - 128][rowb + j] = (h16)facc[rb][cb][j];
        }
      }
    __syncthreads();

    f32x4 sacc[2];
    sacc[0] = (f32x4){0.f, 0.f, 0.f, 0.f};
    sacc[1] = (f32x4){0.f, 0.f, 0.f, 0.f};
    #pragma unroll
    for (int k0 = 0; k0 < 64; k0 += 32) {
      const half8 aq = *(const half8*)&qs[rS + l16][k0 + kg * 8];
      const half8 b0 = *(const half8*)&ks[cS + l16][k0 + kg * 8];
      const half8 b1 = *(const half8*)&ks[cS + 16 + l16][k0 + kg * 8];
      sacc[0] = __builtin_amdgcn_mfma_f32_16x16x32_f16(aq, b0, sacc[0], 0, 0, 0);
      sacc[1] = __builtin_amdgcn_mfma_f32_16x16x32_f16(aq, b1, sacc[1], 0, 0, 0);
    }
    #pragma unroll
    for (int t = 0; t < 2; ++t)
      #pragma unroll
      for (int j = 0; j < 4; ++j)
        sS[rS + kg * 4 + j][cS + t * 16 + l16] = sacc[t][j] * SCALE;
    __syncthreads();

    {
      const int row = tid >> 3, j0 = (tid & 7) * 8;
      float v0[8];
      #pragma unroll
      for (int i = 0; i < 8; ++i) v0[i] = sS[row][j0 + i];
      float m = v0[0];
      #pragma unroll
      for (int i = 1; i < 8; ++i) m = fmaxf(m, v0[i]);
      m = fmaxf(m, __shfl_xor(m, 1));
      m = fmaxf(m, __shfl_xor(m, 2));
      m = fmaxf(m, __shfl_xor(m, 4));
      float e[8], ssum = 0.f;
      #pragma unroll
      for (int i = 0; i < 8; ++i) { e[i] = __expf(v0[i] - m); ssum += e[i]; }
      ssum += __shfl_xor(ssum, 1);
      ssum += __shfl_xor(ssum, 2);
      ssum += __shfl_xor(ssum, 4);
      const float inv = 1.0f / ssum;
      #pragma unroll
      for (int i = 0; i < 8; ++i) qs[row][j0 + i] = (h16)(e[i] * inv);
    }
    __syncthreads();

    f32x4 oacc[2];
    oacc[0] = (f32x4){0.f, 0.f, 0.f, 0.f};
    oacc[1] = (f32x4){0.f, 0.f, 0.f, 0.f};
    #pragma unroll
    for (int k0 = 0; k0 < 64; k0 += 32) {
      const half8 ap = *(const half8*)&qs[rS + l16][k0 + kg * 8];
      const half8 b0 = *(const half8*)&vt[cS + l16][k0 + kg * 8];
      const half8 b1 = *(const half8*)&vt[cS + 16 + l16][k0 + kg * 8];
      oacc[0] = __builtin_amdgcn_mfma_f32_16x16x32_f16(ap, b0, oacc[0], 0, 0, 0);
      oacc[1] = __builtin_amdgcn_mfma_f32_16x16x32_f16(ap, b1, oacc[1], 0, 0, 0);
    }
    #pragma unroll
    for (int t = 0; t < 2; ++t)
      #pragma unroll
      for (int j = 0; j < 4; ++j)
        ks[rS + kg * 4 + j][cS + t * 16 + l16] = (h16)oacc[t][j];
    __syncthreads();

    #pragma unroll
    for (int k0 = 0; k0 < 64; k0 += 32) {
      half8 ah[4];
      #pragma unroll
      for (int rb = 0; rb < 4; ++rb)
        ah[rb] = *(const half8*)&ks[rb * 16 + l16][k0 + kg * 8];
      #pragma unroll
      for (int cb = 0; cb < 6; ++cb) {
        const int ocol = wv * 96 + cb * 16 + l16;
        const half8 bw = loadw8<WT>(wp + (size_t)ocol * 768 + h * 64 + k0 + kg * 8);
        #pragma unroll
        for (int rb = 0; rb < 4; ++rb)
          acc[rb][cb] = __builtin_amdgcn_mfma_f32_16x16x32_f16(ah[rb], bw, acc[rb][cb], 0, 0, 0);
      }
    }
    __syncthreads();
  }

  float* og = out + (size_t)g * (64 * 768);
  #pragma unroll
  for (int rb = 0; rb < 4; ++rb)
    #pragma unroll
    for (int cb = 0; cb < 6; ++cb) {
      const int col = wv * 96 + cb * 16 + l16;
      #pragma unroll
      for (int j = 0; j < 4; ++j) {
        const int row = rb * 16 + kg * 4 + j;
        og[(size_t)row * 768 + col] = acc[rb][cb][j] + bcol[cb];
      }
    }
}

// ---------------------------------------------------------------- launch
extern "C" void kernel_launch(void* const* d_in, const int* in_sizes, int n_in,
                              void* d_out, int out_size, void* d_ws, size_t ws_size,
                              hipStream_t stream) {
  const float* x     = (const float*)d_in[0];
  const float* wqkv  = (const float*)d_in[1];
  const float* wproj = (const float*)d_in[2];
  const float* bias  = (const float*)d_in[3];
  float* out = (float*)d_out;

  const size_t SZ_WQ  = (size_t)2304 * 768 * sizeof(h16);
  const size_t SZ_WP  = (size_t)768 * 768 * sizeof(h16);
  const size_t SZ_XH  = (size_t)65536 * 768 * sizeof(h16);
  const size_t SZ_QKV = (size_t)65536 * 2304 * sizeof(h16);

  if (ws_size >= SZ_WQ + SZ_WP + SZ_XH + SZ_QKV) {
    h16* wq16 = (h16*)d_ws;
    h16* wp16 = (h16*)((char*)d_ws + SZ_WQ);
    h16* xh   = (h16*)((char*)d_ws + SZ_WQ + SZ_WP);
    h16* qkv  = (h16*)((char*)d_ws + SZ_WQ + SZ_WP + SZ_XH);

    prep_cvt<<<2048, 256, 0, stream>>>(wqkv, wproj, x, wq16, wp16, xh);
    gemm8<false, h16><<<2304, 512, 0, stream>>>(xh, 768, wq16, 768, nullptr, qkv, 2304, 9);
    attn64<<<12288, 256, 0, stream>>>(qkv);
    gemm8<true, float><<<768, 512, 0, stream>>>(qkv, 2304, wp16, 768, bias, out, 768, 3);
  } else if (ws_size >= SZ_WQ + SZ_WP) {
    h16* wq16 = (h16*)d_ws;
    h16* wp16 = (h16*)((char*)d_ws + SZ_WQ);
    prep_w_only<<<1024, 256, 0, stream>>>(wqkv, wproj, wq16, wp16);
    fused_fb<h16><<<1024, 512, 0, stream>>>(x, wq16, wp16, bias, out);
  } else {
    fused_fb<float><<<1024, 512, 0, stream>>>(x, wqkv, wproj, bias, out);
  }
}